// Round 14
// baseline (2104.664 us; speedup 1.0000x reference)
//
#include <hip/hip_runtime.h>

#define B_ 64
#define T_ 512
#define D_ 32
#define U_ 512
#define SIGD 1056

typedef _Float16 half8 __attribute__((ext_vector_type(8)));
typedef float f32x4 __attribute__((ext_vector_type(4)));
typedef unsigned int u32x4 __attribute__((ext_vector_type(4)));
typedef unsigned short ushort_t;
typedef unsigned int uint_t;
typedef unsigned long long ull_t;

// ---- workspace layout (bytes) ----
#define SIG_OFF   0ull            // fp16 norm_sigs  [b*512+t][1056]           69,206,016
#define F_OFF     69206016ull     // fp16 f_all      [t][u][b]                 33,554,432
#define HB2_OFF   102760448ull    // tagged h dbuf 2 x [64 rows][256 pairs] x 8B  262,144
#define A_OFF     136314880ull    // fp32 a          [b][t][i]                  4,194,304
#define DX_OFF    140509184ull    // fp32 dx         [b][t][i]                  4,194,304
#define X16_OFF   144703488ull    // fp16 x          [t][b][i]                  2,097,152
#define R16_OFF   146800640ull    // fp16 [R;Wi]     [k=544][n=1536]            1,671,168
#define WF16_OFF  148471808ull    // fp16 Wf         [k=1056][n=512]            1,081,344

// ============ K0: dx / a / x16 precompute + zero tagged h buffer ============
__global__ __launch_bounds__(256) void k_prep(const float* __restrict__ x,
                                              _Float16* x16, float* a_buf, float* dx_buf,
                                              uint_t* hb2) {
  int b = blockIdx.x;
  int tid = threadIdx.x;
  if (b >= 64) {  // blocks 64..67: zero hb2 (65536 u32 = 256KB) — kills stale tags
    for (int gi = (b - 64) * 256 + tid; gi < 65536; gi += 1024) hb2[gi] = 0u;
    return;
  }
  if (tid >= 32) return;
  int i = tid;
  float xprev = x[(b * T_) * D_ + i];
  x16[(0 * B_ + b) * D_ + i] = (_Float16)xprev;
  a_buf[(b * T_) * D_ + i] = 0.f;
  dx_buf[(b * T_) * D_ + i] = 0.f;
  float S1 = 0.f;
  for (int t = 1; t < T_; ++t) {
    float xv = x[(b * T_ + t) * D_ + i];
    float dx = xv - xprev;
    float a = S1 + 0.5f * dx;
    S1 += dx;
    a_buf[(b * T_ + t) * D_ + i] = a;
    dx_buf[(b * T_ + t) * D_ + i] = dx;
    x16[(t * B_ + b) * D_ + i] = (_Float16)xv;
    xprev = xv;
  }
}

// ============ K0b: weight fp16 conversion ============
__global__ __launch_bounds__(256) void k_weights(const float* __restrict__ rk,
                                                 const float* __restrict__ ik,
                                                 const float* __restrict__ fk,
                                                 _Float16* R16t, _Float16* Wf16) {
  int e = (blockIdx.x * 256 + threadIdx.x) * 4;
  if (e < 835584) {
    const float* src = (e < 786432) ? (rk + e) : (ik + (e - 786432));
#pragma unroll
    for (int j = 0; j < 4; ++j) R16t[e + j] = (_Float16)src[j];
  } else {
    int e2 = e - 835584;  // < 540672
#pragma unroll
    for (int j = 0; j < 4; ++j) Wf16[e2 + j] = (_Float16)fk[e2 + j];
  }
}

// ============ K1: signature stream -> normalized fp16 sig matrix ============
__global__ __launch_bounds__(1024) void k_sig(const float* __restrict__ a_buf,
                                              const float* __restrict__ dx_buf,
                                              _Float16* __restrict__ sig) {
  int b = blockIdx.x;
  int tid = threadIdx.x;
  int i = tid >> 5, j = tid & 31;
  __shared__ float a_ch[32][32];
  __shared__ float dx_ch[32][32];
  float S2 = 0.f;
  for (int t0 = 0; t0 < T_; t0 += 32) {
    a_ch[i][j]  = a_buf[(b * T_ + t0 + i) * D_ + j];
    dx_ch[i][j] = dx_buf[(b * T_ + t0 + i) * D_ + j];
    __syncthreads();
#pragma unroll 4
    for (int tt = 0; tt < 32; ++tt) {
      int t = t0 + tt;
      S2 += a_ch[tt][i] * dx_ch[tt][j];
      float inv = (t == 0) ? 0.f : (1.0f / (float)t);
      int row = b * T_ + t;
      sig[row * SIGD + 32 + i * 32 + j] = (_Float16)(S2 * inv);
      if (i == 0) {
        float s1 = a_ch[tt][j] + 0.5f * dx_ch[tt][j];
        sig[row * SIGD + j] = (_Float16)(s1 * inv);
      }
    }
    __syncthreads();
  }
}

// ============ K2: f_all = sigmoid(sig @ Wf + b_f), fp16 MFMA, out [t][u][b] ============
__global__ __launch_bounds__(256) void k_fgemm(const _Float16* __restrict__ sig,
                                               const _Float16* __restrict__ Wf16,
                                               const float* __restrict__ bias,
                                               _Float16* __restrict__ f_buf) {
  const int tid = threadIdx.x;
  const int m0 = blockIdx.x * 64;
  const int n0 = blockIdx.y * 128;
  __shared__ __align__(16) ushort_t As[64 * 40];
  __shared__ __align__(16) ushort_t Bs[128 * 40];
  const uint_t* sig32 = (const uint_t*)sig;
  const uint_t* w32 = (const uint_t*)Wf16;
  f32x4 acc[8];
#pragma unroll
  for (int nt = 0; nt < 8; ++nt) acc[nt] = f32x4{0.f, 0.f, 0.f, 0.f};
  const int lane = tid & 63, w = tid >> 6;
  const int cl = lane & 15, q8 = (lane >> 4) * 8;
  for (int kt = 0; kt < 33; ++kt) {
#pragma unroll
    for (int it = 0; it < 4; ++it) {
      int idx = tid + (it << 8);
      int row = idx >> 4, kp = idx & 15;
      uint_t v = sig32[(m0 + row) * 528 + kt * 16 + kp];
      *(uint_t*)&As[row * 40 + kp * 2] = v;
    }
#pragma unroll
    for (int it = 0; it < 8; ++it) {
      int idx = tid + (it << 8);
      int kr = idx >> 6, np = idx & 63;
      uint_t v = w32[(kt * 32 + kr) * 256 + (n0 >> 1) + np];
      Bs[(np * 2) * 40 + kr] = (ushort_t)(v & 0xffffu);
      Bs[(np * 2 + 1) * 40 + kr] = (ushort_t)(v >> 16);
    }
    __syncthreads();
    half8 a = *(const half8*)&As[(w * 16 + cl) * 40 + q8];
#pragma unroll
    for (int nt = 0; nt < 8; ++nt) {
      half8 bfr = *(const half8*)&Bs[(nt * 16 + cl) * 40 + q8];
      acc[nt] = __builtin_amdgcn_mfma_f32_16x16x32_f16(a, bfr, acc[nt], 0, 0, 0);
    }
    __syncthreads();
  }
#pragma unroll
  for (int nt = 0; nt < 8; ++nt) {
    int col = n0 + nt * 16 + cl;
    float bf = bias[512 + col];
#pragma unroll
    for (int r = 0; r < 4; ++r) {
      int m = m0 + w * 16 + ((lane >> 4) << 2) + r;
      int t = m & 511, b = m >> 9;
      float z = acc[nt][r] + bf;
      float fv = 1.f / (1.f + __expf(-z));
      f_buf[(t * 512 + col) * 64 + b] = (_Float16)fv;
    }
  }
}

// ============ K3: batch-partitioned persistent LSTM scan ============
// 64 blocks = 8 groups (G = bid&7). R14: merge detect into the stage.
// Producer: tagged 8B atomic entries (h_dword | (t+1)<<32) via the R11
// coalesced transpose — ONE store_dwordx2 per wave, NO drain, NO counter.
// Consumer: R13's cooperative stage but tagged — each thread loads its 64B
// (4 x dwordx4 = 8 entries) of the group's 16KB slab, checks the 8 embedded
// tags, selectively retries only stale chunks (bounded), packs data words
// into the double-buffered LDS slab, barrier, MFMAs read LDS (unchanged).
// Deletes drain-ack RTT + counter-add + poll-detect (~2-3k cy/step); adds
// <=1-2 cheap coalesced retry RTTs. R6/R9 proved the tagged protocol
// correct; their regression was per-lane refetch traffic, which R13's
// cooperative stage eliminates. Buffer safety: dbuf + per-step barrier
// (a wave reaches t+2's write only after the t+1 barrier, which follows
// every wave's completed step-t reads); 8B single-copy atomicity => a tag
// never precedes its data.
__global__ __launch_bounds__(256, 1) void k_scan(const _Float16* __restrict__ R16t,
                                                 const float* __restrict__ bias,
                                                 const _Float16* __restrict__ f16,
                                                 const _Float16* __restrict__ x16,
                                                 uint_t* hb2,
                                                 float* __restrict__ out) {
  const int tid = threadIdx.x;
  const int bid = blockIdx.x;         // 0..63
  const int G = bid & 7;              // group (batch tile)
  const int lane = tid & 63, w = tid >> 6;
  const int cl = lane & 15, quad = lane >> 4, q8 = quad * 8;
  const int widx = ((bid >> 3) << 2) | w;  // producer-wave index in group, 0..31
  const int u0 = widx * 16;           // unit tile base
  const int u = u0 + cl;              // this lane's unit
  const int b0 = G * 8;               // batch base

  // coalesced-store mapping (R11): lane holds dword (row lane>>3, pair lane&7)
  const int srcl = ((lane >> 5) & 1) * 16 + (lane & 7) * 2;
  const int rsel = (lane >> 3) & 3;

  // LDS h slab: 2 buffers x 8 rows x 1040B (1024 data + 16 pad)
  __shared__ __align__(16) char hlds[2][8 * 1040];

  // B fragments: 3 gates (i,c,o) x 17 ksteps = 204 VGPRs
  half8 bfr[3][17];
#pragma unroll
  for (int g3 = 0; g3 < 3; ++g3)
#pragma unroll
    for (int kk = 0; kk < 17; ++kk)
#pragma unroll
      for (int jj = 0; jj < 8; ++jj)
        bfr[g3][kk][jj] = R16t[(kk * 32 + q8 + jj) * 1536 + g3 * 512 + u];

  const float bi = bias[u];
  const float bc = bias[1024 + u];
  const float bo = bias[1536 + u];
  float c_st[4] = {0.f, 0.f, 0.f, 0.f};

#pragma unroll 1
  for (int t = 0; t < T_; ++t) {
    // ---- issue tagged cooperative stage FIRST (RTT overlaps fpre/xa) ----
    u32x4 q0, q1, q2, q3;
    const char* src = (const char*)hb2 + ((t & 1) ? 131072 : 0)
                    + (unsigned)b0 * 2048 + (unsigned)tid * 64;
#define TLD(Q, OFF) \
    asm volatile("global_load_dwordx4 %0, %1, off offset:" #OFF " sc0 sc1" \
                 : "=&v"(Q) : "v"(src) : "memory")
    if (t > 0) { TLD(q0, 0); TLD(q1, 16); TLD(q2, 32); TLD(q3, 48); }

    // ---- t-dependent, h-independent data (hides under stage RTT) ----
    float fpre[4];
    {
      union { ull_t q; _Float16 h[4]; } fu;
      fu.q = *(const ull_t*)(f16 + ((t * 512 + u) * 64 + b0 + (quad & 1) * 4));
#pragma unroll
      for (int r = 0; r < 4; ++r) fpre[r] = (float)fu.h[r];
    }
    half8 xa = *(const half8*)(x16 + ((t * 64 + b0 + (cl & 7)) * 32 + q8));

    // ---- hoisted x-input MFMAs (kstep 16): no h dependence ----
    f32x4 ai = f32x4{0.f, 0.f, 0.f, 0.f};
    f32x4 ac = f32x4{0.f, 0.f, 0.f, 0.f};
    f32x4 ao = f32x4{0.f, 0.f, 0.f, 0.f};
    ai = __builtin_amdgcn_mfma_f32_16x16x32_f16(xa, bfr[0][16], ai, 0, 0, 0);
    ac = __builtin_amdgcn_mfma_f32_16x16x32_f16(xa, bfr[1][16], ac, 0, 0, 0);
    ao = __builtin_amdgcn_mfma_f32_16x16x32_f16(xa, bfr[2][16], ao, 0, 0, 0);

    if (t > 0) {
      // ---- tag-validate + selective retry (per-thread, bounded) ----
      const uint_t texp = (uint_t)t;  // producers at t-1 stored tag t
      int rounds = 0;
      for (;;) {
        asm volatile("s_waitcnt vmcnt(0)" ::: "memory");
        __builtin_amdgcn_sched_barrier(0);
        uint_t s0 = (q0[1] ^ texp) | (q0[3] ^ texp);
        uint_t s1 = (q1[1] ^ texp) | (q1[3] ^ texp);
        uint_t s2 = (q2[1] ^ texp) | (q2[3] ^ texp);
        uint_t s3 = (q3[1] ^ texp) | (q3[3] ^ texp);
        if ((s0 | s1 | s2 | s3) == 0u) break;
        if (++rounds > 4096) break;    // bail-forward: terminating, diagnosable
        if (rounds > 8) __builtin_amdgcn_s_sleep(1);
        if (s0) TLD(q0, 0);
        if (s1) TLD(q1, 16);
        if (s2) TLD(q2, 32);
        if (s3) TLD(q3, 48);
      }
      // ---- pack data words -> LDS slab (row tid>>5, 32B at (tid&31)*32) ----
      u32x4 w0{q0[0], q0[2], q1[0], q1[2]};
      u32x4 w1{q2[0], q2[2], q3[0], q3[2]};
      char* dst = &hlds[t & 1][(tid >> 5) * 1040 + (tid & 31) * 32];
      *(u32x4*)dst = w0;
      *(u32x4*)(dst + 16) = w1;
      __syncthreads();
      // ---- 48 h-MFMAs, fragments from LDS (R13-identical) ----
      const char* lbase = &hlds[t & 1][(cl & 7) * 1040 + quad * 16];
#pragma unroll
      for (int kk = 0; kk < 16; ++kk) {
        half8 af = *(const half8*)(lbase + kk * 64);
        ai = __builtin_amdgcn_mfma_f32_16x16x32_f16(af, bfr[0][kk], ai, 0, 0, 0);
        ac = __builtin_amdgcn_mfma_f32_16x16x32_f16(af, bfr[1][kk], ac, 0, 0, 0);
        ao = __builtin_amdgcn_mfma_f32_16x16x32_f16(af, bfr[2][kk], ao, 0, 0, 0);
      }
    }
#undef TLD

    // ---- epilogue: gates -> c,h (all 64 lanes valid; quads 2,3 = dup rows) ----
    ushort_t hu0, hu1, hu2, hu3;
#define EPI_R(r, HU) { \
      float iv = 1.f / (1.f + __expf(-(ai[r] + bi))); \
      float cv = 1.f - 2.f / (__expf(2.f * (ac[r] + bc)) + 1.f); \
      float ov = 1.f / (1.f + __expf(-(ao[r] + bo))); \
      float c = fpre[r] * c_st[r] + iv * cv; \
      c_st[r] = c; \
      float h = ov * (1.f - 2.f / (__expf(2.f * c) + 1.f)); \
      HU = __builtin_bit_cast(ushort_t, (_Float16)h); \
      if (t == T_ - 1) { \
        int brow = (quad << 2) + r; \
        if (brow < 8) out[((b0 + brow) << 9) + u] = h; \
      } \
    }
    EPI_R(0, hu0) EPI_R(1, hu1) EPI_R(2, hu2) EPI_R(3, hu3)
#undef EPI_R

    if (t < T_ - 1) {
      // ---- in-register transpose (R11) -> ONE tagged 8B store per lane ----
      uint_t d0 = ((uint_t)(ushort_t)__shfl((int)hu0, srcl) & 0xffffu) |
                  ((uint_t)(ushort_t)__shfl((int)hu0, srcl + 1) << 16);
      uint_t d1 = ((uint_t)(ushort_t)__shfl((int)hu1, srcl) & 0xffffu) |
                  ((uint_t)(ushort_t)__shfl((int)hu1, srcl + 1) << 16);
      uint_t d2 = ((uint_t)(ushort_t)__shfl((int)hu2, srcl) & 0xffffu) |
                  ((uint_t)(ushort_t)__shfl((int)hu2, srcl + 1) << 16);
      uint_t d3 = ((uint_t)(ushort_t)__shfl((int)hu3, srcl) & 0xffffu) |
                  ((uint_t)(ushort_t)__shfl((int)hu3, srcl + 1) << 16);
      uint_t dd = (rsel == 0) ? d0 : (rsel == 1) ? d1 : (rsel == 2) ? d2 : d3;
      int row = b0 + (lane >> 3);                      // global batch row
      ull_t pk = (ull_t)dd | ((ull_t)(uint_t)(t + 1) << 32);
      ull_t* p = (ull_t*)((char*)hb2 + ((t & 1) ? 0 : 131072)
                          + (unsigned)row * 2048 + ((u0 >> 1) + (lane & 7)) * 8);
      __hip_atomic_store(p, pk, __ATOMIC_RELAXED, __HIP_MEMORY_SCOPE_AGENT);
      // no drain, no counter: tags self-announce; acks overlap next stage
    }
  }
}

extern "C" void kernel_launch(void* const* d_in, const int* in_sizes, int n_in,
                              void* d_out, int out_size, void* d_ws, size_t ws_size,
                              hipStream_t stream) {
  const float* x = (const float*)d_in[0];
  const float* ik = (const float*)d_in[1];
  const float* rk = (const float*)d_in[2];
  const float* fk = (const float*)d_in[3];
  const float* bias = (const float*)d_in[4];
  char* ws = (char*)d_ws;
  _Float16* sig = (_Float16*)(ws + SIG_OFF);
  _Float16* f_buf = (_Float16*)(ws + F_OFF);
  uint_t* hb2 = (uint_t*)(ws + HB2_OFF);
  float* a_buf = (float*)(ws + A_OFF);
  float* dx_buf = (float*)(ws + DX_OFF);
  _Float16* x16 = (_Float16*)(ws + X16_OFF);
  _Float16* R16t = (_Float16*)(ws + R16_OFF);
  _Float16* Wf16 = (_Float16*)(ws + WF16_OFF);
  float* out = (float*)d_out;

  hipLaunchKernelGGL(k_prep, dim3(68), dim3(256), 0, stream, x, x16, a_buf, dx_buf, hb2);
  hipLaunchKernelGGL(k_weights, dim3(1344), dim3(256), 0, stream, rk, ik, fk, R16t, Wf16);
  hipLaunchKernelGGL(k_sig, dim3(64), dim3(1024), 0, stream, a_buf, dx_buf, sig);
  hipLaunchKernelGGL(k_fgemm, dim3(512, 4), dim3(256), 0, stream, sig, Wf16, bias, f_buf);
  hipLaunchKernelGGL(k_scan, dim3(64), dim3(256), 0, stream, R16t, bias, f_buf,
                     x16, hb2, out);
}